// Round 7
// baseline (362.622 us; speedup 1.0000x reference)
//
#include <hip/hip_runtime.h>
#include <hip/hip_bf16.h>
#include <stdint.h>

#define NROWS 8192
#define DDIM  256
#define SIGMA_INV 10.0f

#define BM 32                     // 16 rows/wave -> qa 32 VGPR, oacc 32 acc
#define BN 64
#define NSPLIT 4                  // chunk=b&3; XCD=b%8 -> one 2MB j-slice per XCD
                                  // (L2-resident, round-2 lesson). 1024 blocks =
                                  // exactly 4/CU; same-CU blocks share chunk
                                  // (b+256 preserves b&3) -> shared kn/vt lines.
#define JCHUNK (NROWS / NSPLIT)   // 2048
#define NITER  (JCHUNK / BN)      // 32
#define PSTR   72                 // pl row stride in halfs (144B, 16B-aligned)
#define KCHB   1056               // DMA chunk pitch: 1024B payload + 32B pad

typedef __attribute__((ext_vector_type(8))) short bf16x8;
typedef __attribute__((ext_vector_type(4))) float f32x4;

__device__ inline unsigned short f2bf(float x) {
  __hip_bfloat16 h = __float2bfloat16(x);
  return *reinterpret_cast<unsigned short*>(&h);
}

__device__ inline void dma16(const void* g, void* l) {
  __builtin_amdgcn_global_load_lds(
      (const __attribute__((address_space(1))) unsigned int*)g,
      (__attribute__((address_space(3))) unsigned int*)l, 16, 0, 0);
}

// ---------------- K0: L2-normalize rows -> bf16 ----------------
__global__ __launch_bounds__(256) void normalize_k(const float* __restrict__ emb,
                                                   unsigned short* __restrict__ embn) {
  const int w = threadIdx.x >> 6, lane = threadIdx.x & 63;
  const int row = blockIdx.x * 4 + w;
  const float4* src = (const float4*)(emb + (size_t)row * DDIM);
  float4 v = src[lane];
  float ss = v.x * v.x + v.y * v.y + v.z * v.z + v.w * v.w;
  for (int off = 32; off >= 1; off >>= 1) ss += __shfl_xor(ss, off);
  const float sc = 1.0f / fmaxf(sqrtf(ss), 1e-12f);
  ushort4 o;
  o.x = f2bf(v.x * sc); o.y = f2bf(v.y * sc);
  o.z = f2bf(v.z * sc); o.w = f2bf(v.w * sc);
  ((ushort4*)(embn + (size_t)row * DDIM))[lane] = o;
}

// ---------------- K0b: emb[N][D] fp32 -> vt TILED bf16 ----------------
// vt layout: [jtile = j/64][d = 0..255][jj = j%64]  (32KB contiguous per j-tile)
__global__ __launch_bounds__(256) void transpose_k(const float* __restrict__ emb,
                                                   unsigned short* __restrict__ vt) {
  __shared__ float tile[64][65];
  const int r0 = blockIdx.x * 64, c0 = blockIdx.y * 64;
  const int tr = threadIdx.x >> 6, tc = threadIdx.x & 63;
  for (int i = 0; i < 16; ++i)
    tile[i * 4 + tr][tc] = emb[(size_t)(r0 + i * 4 + tr) * DDIM + c0 + tc];
  __syncthreads();
  unsigned short* dst = vt + (size_t)(r0 >> 6) * (DDIM * 64);   // jtile = r0/64
  for (int i = 0; i < 16; ++i)
    dst[(size_t)(c0 + i * 4 + tr) * 64 + tc] = f2bf(tile[tc][i * 4 + tr]);
}

// ---------------- F: fused  S=Qn.Knt -> exp -> O += P.V, row sums ----------------
// ROUND-7: cross the HW occupancy BIN boundary (waves/SIMD = 8/4/2 at total regs
// <=64/<=128/<=256 -- learn_hip m69; reconciles ALL six prior rounds: R0/3/6 at
// 128+64acc=192 -> 2-wave bin; R5 at 112+32acc=144 -> STILL 2-wave bin, which is
// why its occupancy never moved; R1/4's (256,3) hint targeted the 128 bin with a
// 192-reg design -> spills). This design fits 128 TOTAL by construction:
//   qa 32 + oacc 32(acc) + sacc 8 + vf quad 16 + addressing ~= 110-125.
// launch_bounds(256,4) = budget 128 total = the 4-wave bin. Demand <= budget ->
// no spill expected. ABORT CRITERION: VGPR>96 or FETCH>100MB -> spilled -> the
// occupancy direction is dead.
// grid = 256 mblk x 4 chunks = 1024 blocks = exactly 4 blocks/CU, all resident.
// G2 V-frags in QUADS (4 loads + 4 MFMA) to cap live vf regs.
__global__ __launch_bounds__(256, 4) void fused_k(
    const unsigned short* __restrict__ embn,  // [N][D] bf16 normalized
    const unsigned short* __restrict__ vt,    // tiled [N/64][256][64] bf16
    float* __restrict__ out,                  // [N][D] fp32, pre-zeroed, atomic accum
    float* __restrict__ l_part)               // [N] fp32, pre-zeroed, atomic accum
{
  __shared__ char kn[32 * KCHB];              // 33 KB, padded DMA-staged K-tile
  __shared__ unsigned short pl[BM * PSTR];    // 4.6 KB, P transit

  const int tid = threadIdx.x;
  const int w = tid >> 6, lane = tid & 63;
  const int mg = w >> 1, dh = w & 1;          // m-group (16 rows), d-half
  const int q = lane >> 4, c = lane & 15;
  const int chunk = blockIdx.x & 3;
  const int mblk = blockIdx.x >> 2;
  const int row0 = mblk * BM + mg * 16;       // this wave's 16 rows
  const int t0 = chunk * NITER;
  const int t1 = t0 + NITER;

  // Q fragments resident: A[m=c][k=q*8+j]  (32 VGPR)
  bf16x8 qa[8];
  for (int k = 0; k < 8; ++k)
    qa[k] = *(const bf16x8*)(embn + (size_t)(row0 + c) * DDIM + k * 32 + q * 8);

  f32x4 oacc[8];                              // 32 acc regs
  for (int u = 0; u < 8; ++u) oacc[u] = {0.f, 0.f, 0.f, 0.f};
  float lacc[4] = {};

  // prologue: stage first K-tile (32 x 1KB chunks at 1056B pitch, 8 per wave)
  {
    const char* src = (const char*)(embn + (size_t)t0 * BN * DDIM);
    for (int cc = 0; cc < 8; ++cc) {
      const int ch = w * 8 + cc;
      dma16(src + ch * 1024 + lane * 16, kn + ch * KCHB + lane * 16);
    }
  }

  // kn row r (512B payload) lives at (r>>1)*KCHB + (r&1)*512
  for (int it = t0; it < t1; ++it) {
    __syncthreads();  // B1: DMA(it) drained (vmcnt0); pl reads of it-1 drained

    // ---- G1: S[16x32] = Q . Kn^T (this wave: rows mg*16+, cols dh*32+) ----
    f32x4 sacc[2];
    sacc[0] = {0.f, 0.f, 0.f, 0.f};
    sacc[1] = {0.f, 0.f, 0.f, 0.f};
    const int rb0 = (dh * 16 + (c >> 1)) * KCHB + (c & 1) * 512;        // kn row dh*32+c
    const int rb1 = (dh * 16 + 8 + (c >> 1)) * KCHB + (c & 1) * 512;    // kn row dh*32+16+c
    for (int k = 0; k < 8; ++k) {
      bf16x8 b0 = *(const bf16x8*)(kn + rb0 + k * 64 + q * 16);
      bf16x8 b1 = *(const bf16x8*)(kn + rb1 + k * 64 + q * 16);
      sacc[0] = __builtin_amdgcn_mfma_f32_16x16x32_bf16(qa[k], b0, sacc[0], 0, 0, 0);
      sacc[1] = __builtin_amdgcn_mfma_f32_16x16x32_bf16(qa[k], b1, sacc[1], 0, 0, 0);
    }

    // exp (fixed shift 10; cos<=1 so logits<=10, softmax shift-invariant) + P + row sums
    for (int nt = 0; nt < 2; ++nt)
      for (int r = 0; r < 4; ++r) {
        const float p = __expf(fmaf(SIGMA_INV, sacc[nt][r], -SIGMA_INV));
        lacc[r] += p;
        // C/D layout: row = q*4+r, col = c
        pl[(mg * 16 + q * 4 + r) * PSTR + dh * 32 + nt * 16 + c] = f2bf(p);
      }

    const unsigned short* vtile = vt + (size_t)it * (DDIM * BN);

    // vf quad 0 (kk=0, u=0..3): issued pre-B2, rides through the barrier
    bf16x8 vq0[4];
    for (int u = 0; u < 4; ++u)
      vq0[u] = *(const bf16x8*)(vtile + (size_t)(dh * 128 + u * 16 + c) * BN + q * 8);

    // B2 RAW barrier: pl writes + kn ds_reads retired (lgkmcnt only); NO vmem drain.
    __builtin_amdgcn_sched_barrier(0);
    asm volatile("s_waitcnt lgkmcnt(0)" ::: "memory");
    __builtin_amdgcn_sched_barrier(0);
    __builtin_amdgcn_s_barrier();
    __builtin_amdgcn_sched_barrier(0);

    // ---- G2: O[16x128] += P[16x64] . V[64x128], in quads ----
    // oacc[u] covers out cols dh*128 + u*16 (u = 0..7); each oacc[u] gets
    // contributions from kk=0 (vq0/vq1) and kk=1 (vq2/vq3).
    {
      bf16x8 ap0 = *(const bf16x8*)(pl + (mg * 16 + c) * PSTR + q * 8);
      bf16x8 vq1[4];
      for (int u = 0; u < 4; ++u)
        vq1[u] = *(const bf16x8*)(vtile + (size_t)(dh * 128 + (u + 4) * 16 + c) * BN + q * 8);
      for (int u = 0; u < 4; ++u)
        oacc[u] = __builtin_amdgcn_mfma_f32_16x16x32_bf16(ap0, vq0[u], oacc[u], 0, 0, 0);
      bf16x8 vq2[4];
      for (int u = 0; u < 4; ++u)
        vq2[u] = *(const bf16x8*)(vtile + (size_t)(dh * 128 + u * 16 + c) * BN + 32 + q * 8);
      for (int u = 0; u < 4; ++u)
        oacc[u + 4] = __builtin_amdgcn_mfma_f32_16x16x32_bf16(ap0, vq1[u], oacc[u + 4], 0, 0, 0);
      bf16x8 ap1 = *(const bf16x8*)(pl + (mg * 16 + c) * PSTR + 32 + q * 8);
      bf16x8 vq3[4];
      for (int u = 0; u < 4; ++u)
        vq3[u] = *(const bf16x8*)(vtile + (size_t)(dh * 128 + (u + 4) * 16 + c) * BN + 32 + q * 8);
      for (int u = 0; u < 4; ++u)
        oacc[u] = __builtin_amdgcn_mfma_f32_16x16x32_bf16(ap1, vq2[u], oacc[u], 0, 0, 0);

      // stage NEXT K-tile before the last quad (kn reads retired at B2).
      // Issued AFTER all vf loads -> waiting on vq3 (vmcnt<=8) leaves the
      // 8 DMA loads in flight to the next B1.
      if (it + 1 < t1) {
        const char* src = (const char*)(embn + (size_t)(it + 1) * BN * DDIM);
        for (int cc = 0; cc < 8; ++cc) {
          const int ch = w * 8 + cc;
          dma16(src + ch * 1024 + lane * 16, kn + ch * KCHB + lane * 16);
        }
      }

      for (int u = 0; u < 4; ++u)
        oacc[u + 4] = __builtin_amdgcn_mfma_f32_16x16x32_bf16(ap1, vq3[u], oacc[u + 4], 0, 0, 0);
    }
  }

  // epilogue: row sums across the 16 c-lanes, then device atomics
  for (int r = 0; r < 4; ++r) {
    float s = lacc[r];
    s += __shfl_xor(s, 1); s += __shfl_xor(s, 2);
    s += __shfl_xor(s, 4); s += __shfl_xor(s, 8);
    if (c == 0)
      atomicAdd(&l_part[row0 + q * 4 + r], s);
  }
  for (int u = 0; u < 8; ++u)
    for (int r = 0; r < 4; ++r)
      atomicAdd(&out[(size_t)(row0 + q * 4 + r) * DDIM + dh * 128 + u * 16 + c],
                oacc[u][r]);
}

// ---------------- K4: divide by row sums ----------------
__global__ __launch_bounds__(256) void finalize_k(float* __restrict__ out,
                                                  const float* __restrict__ l_part) {
  const int row = blockIdx.x, t = threadIdx.x;
  out[(size_t)row * DDIM + t] /= l_part[row];
}

extern "C" void kernel_launch(void* const* d_in, const int* in_sizes, int n_in,
                              void* d_out, int out_size, void* d_ws, size_t ws_size,
                              hipStream_t stream) {
  const float* emb = (const float*)d_in[0];
  float* out = (float*)d_out;
  char* ws = (char*)d_ws;
  // ws layout: embn 4MB | vt 4MB | l_part 32KB
  unsigned short* embn = (unsigned short*)ws;
  unsigned short* vt   = (unsigned short*)(ws + ((size_t)4 << 20));
  float* l_part        = (float*)(ws + ((size_t)8 << 20));

  hipMemsetAsync(out, 0, (size_t)NROWS * DDIM * sizeof(float), stream);
  hipMemsetAsync(l_part, 0, (size_t)NROWS * sizeof(float), stream);

  normalize_k<<<NROWS / 4, 256, 0, stream>>>(emb, embn);
  transpose_k<<<dim3(NROWS / 64, DDIM / 64), 256, 0, stream>>>(emb, vt);
  fused_k<<<(NROWS / BM) * NSPLIT, 256, 0, stream>>>(embn, vt, out, l_part);
  finalize_k<<<NROWS, 256, 0, stream>>>(out, l_part);
}